// Round 4
// baseline (202.658 us; speedup 1.0000x reference)
//
#include <hip/hip_runtime.h>
#include <math.h>

#define EPS 1e-8f

typedef __attribute__((ext_vector_type(8))) short bf16x8;
typedef __attribute__((ext_vector_type(16))) float f32x16;

__device__ __forceinline__ unsigned short f2bf(float f) {
    unsigned int u = __float_as_uint(f);
    unsigned int r = (u + 0x7fffu + ((u >> 16) & 1u)) >> 16;
    return (unsigned short)r;
}
__device__ __forceinline__ float bf2f(unsigned short h) {
    return __uint_as_float(((unsigned int)h) << 16);
}

// ---------------------------------------------------------------------------
// Prep: normalize each patch vector, split into bf16 hi/lo, store in the
// 32x32x16 MFMA fragment order:
//   off(img, tile t, kstep s, lane l, e) = (((img*8 + t)*4 + s)*64 + l)*8 + e
// holding X[img, patch = t*32 + (l&31), d = s*16 + (l>>5)*8 + e].
// Serves BOTH A- and B-operands of mfma_f32_32x32x16_bf16 for D = X * Y^T.
// (Layout verified correct by round-3 first-call pass.)
// ---------------------------------------------------------------------------
__global__ __launch_bounds__(256) void prep_kernel(
    const float* __restrict__ normal, const float* __restrict__ defect,
    unsigned short* __restrict__ fragN_hi, unsigned short* __restrict__ fragN_lo,
    unsigned short* __restrict__ fragD_hi, unsigned short* __restrict__ fragD_lo)
{
    const int gimg = blockIdx.x;          // 0..127
    const bool isN = gimg < 64;
    const int img  = isN ? gimg : gimg - 64;
    const float* src = isN ? normal : defect;
    unsigned short* dhi = isN ? fragN_hi : fragD_hi;
    unsigned short* dlo = isN ? fragN_lo : fragD_lo;

    const int patch = threadIdx.x;
    const float4* xp = (const float4*)(src + ((size_t)img * 256 + patch) * 64);
    float x[64];
    float ss = 0.f;
    #pragma unroll
    for (int k = 0; k < 16; ++k) {
        float4 v = xp[k];
        x[4*k+0] = v.x; x[4*k+1] = v.y; x[4*k+2] = v.z; x[4*k+3] = v.w;
        ss += v.x*v.x + v.y*v.y + v.z*v.z + v.w*v.w;
    }
    const float inv = 1.f / (sqrtf(ss) + EPS);

    const int t  = patch >> 5;   // tile of 32 patches
    const int l0 = patch & 31;   // lane within first k-group
    #pragma unroll
    for (int s = 0; s < 4; ++s) {
        const size_t base = (((size_t)img * 8 + t) * 4 + s) * 64;
        #pragma unroll
        for (int g = 0; g < 2; ++g) {           // k-group: lanes l0 and l0+32
            const size_t off = (base + (g * 32 + l0)) * 8;
            unsigned short h8[8], l8[8];
            #pragma unroll
            for (int e = 0; e < 8; ++e) {
                const float v = x[s*16 + g*8 + e] * inv;
                const unsigned short hb = f2bf(v);
                h8[e] = hb;
                l8[e] = f2bf(v - bf2f(hb));
            }
            *(uint4*)(dhi + off) = *(const uint4*)h8;
            *(uint4*)(dlo + off) = *(const uint4*)l8;
        }
    }
}

// ---------------------------------------------------------------------------
// One block per image pair; 4 waves; wave w owns p-row-tiles {2w, 2w+1}.
// 3-term split-bf16 emulation of the fp32 dot via 32x32x16 MFMA.
// Register double-buffer on B-fragments; #pragma unroll 1 keeps the loop
// rolled so VGPR stays bounded (no spill -> no scratch -> graph-replay safe).
// ---------------------------------------------------------------------------
__global__ __launch_bounds__(256) void mfma_sim_kernel(
    const unsigned short* __restrict__ fragN_hi, const unsigned short* __restrict__ fragN_lo,
    const unsigned short* __restrict__ fragD_hi, const unsigned short* __restrict__ fragD_lo,
    float* __restrict__ sim)
{
    const int t = threadIdx.x;
    const int l = t & 63;
    const int w = t >> 6;
    const int pair = blockIdx.x;
    const int i  = pair >> 7;
    const int j2 = pair & 127;
    const bool is_nn = (j2 < 64);
    const int j  = is_nn ? j2 : (j2 - 64);
    const unsigned short* bhi_base = is_nn ? fragN_hi : fragD_hi;
    const unsigned short* blo_base = is_nn ? fragN_lo : fragD_lo;

    // A-fragments: 2 row-tiles x 4 k-steps (hi/lo)
    bf16x8 ah[2][4], al[2][4];
    #pragma unroll
    for (int r = 0; r < 2; ++r) {
        #pragma unroll
        for (int s = 0; s < 4; ++s) {
            const size_t off = ((((size_t)i * 8 + (w*2 + r)) * 4 + s) * 64 + l) * 8;
            ah[r][s] = *(const bf16x8*)(fragN_hi + off);
            al[r][s] = *(const bf16x8*)(fragN_lo + off);
        }
    }

    f32x16 rowmax[2];
    #pragma unroll
    for (int r = 0; r < 2; ++r)
        #pragma unroll
        for (int e = 0; e < 16; ++e) rowmax[r][e] = -3e38f;

    const size_t jbase = (size_t)j * 8;

    // double-buffered B fragments (named buffers -> static indexing, rule #20)
    bf16x8 bh0[4], bl0[4], bh1[4], bl1[4];
    #pragma unroll
    for (int s = 0; s < 4; ++s) {
        const size_t off = ((jbase * 4 + s) * 64 + l) * 8;    // c = 0
        bh0[s] = *(const bf16x8*)(bhi_base + off);
        bl0[s] = *(const bf16x8*)(blo_base + off);
    }

    #pragma unroll 1
    for (int c = 0; c < 8; c += 2) {
        // prefetch tile c+1 into buf1 (c+1 <= 7 always)
        #pragma unroll
        for (int s = 0; s < 4; ++s) {
            const size_t off = (((jbase + c + 1) * 4 + s) * 64 + l) * 8;
            bh1[s] = *(const bf16x8*)(bhi_base + off);
            bl1[s] = *(const bf16x8*)(blo_base + off);
        }
        // compute with buf0 (tile c)
        #pragma unroll
        for (int r = 0; r < 2; ++r) {
            f32x16 acc;
            #pragma unroll
            for (int e = 0; e < 16; ++e) acc[e] = 0.f;
            #pragma unroll
            for (int s = 0; s < 4; ++s) {
                acc = __builtin_amdgcn_mfma_f32_32x32x16_bf16(al[r][s], bh0[s], acc, 0, 0, 0);
                acc = __builtin_amdgcn_mfma_f32_32x32x16_bf16(ah[r][s], bl0[s], acc, 0, 0, 0);
                acc = __builtin_amdgcn_mfma_f32_32x32x16_bf16(ah[r][s], bh0[s], acc, 0, 0, 0);
            }
            #pragma unroll
            for (int e = 0; e < 16; ++e)
                rowmax[r][e] = fmaxf(rowmax[r][e], acc[e]);
        }
        // prefetch tile c+2 into buf0 (skip on last iteration)
        if (c < 6) {
            #pragma unroll
            for (int s = 0; s < 4; ++s) {
                const size_t off = (((jbase + c + 2) * 4 + s) * 64 + l) * 8;
                bh0[s] = *(const bf16x8*)(bhi_base + off);
                bl0[s] = *(const bf16x8*)(blo_base + off);
            }
        }
        // compute with buf1 (tile c+1)
        #pragma unroll
        for (int r = 0; r < 2; ++r) {
            f32x16 acc;
            #pragma unroll
            for (int e = 0; e < 16; ++e) acc[e] = 0.f;
            #pragma unroll
            for (int s = 0; s < 4; ++s) {
                acc = __builtin_amdgcn_mfma_f32_32x32x16_bf16(al[r][s], bh1[s], acc, 0, 0, 0);
                acc = __builtin_amdgcn_mfma_f32_32x32x16_bf16(ah[r][s], bl1[s], acc, 0, 0, 0);
                acc = __builtin_amdgcn_mfma_f32_32x32x16_bf16(ah[r][s], bh1[s], acc, 0, 0, 0);
            }
            #pragma unroll
            for (int e = 0; e < 16; ++e)
                rowmax[r][e] = fmaxf(rowmax[r][e], acc[e]);
        }
    }

    // C layout: col = l&31, row = (reg&3) + 8*(reg>>2) + 4*(l>>5).
    // max over cols = max across each 32-lane half; each row's max then
    // duplicated 32x, so the full-wave sum over-counts by 32.
    float s_sum = 0.f;
    #pragma unroll
    for (int r = 0; r < 2; ++r) {
        #pragma unroll
        for (int e = 0; e < 16; ++e) {
            float v = rowmax[r][e];
            v = fmaxf(v, __shfl_xor(v, 1));
            v = fmaxf(v, __shfl_xor(v, 2));
            v = fmaxf(v, __shfl_xor(v, 4));
            v = fmaxf(v, __shfl_xor(v, 8));
            v = fmaxf(v, __shfl_xor(v, 16));
            s_sum += v;
        }
    }
    #pragma unroll
    for (int off = 1; off < 64; off <<= 1)
        s_sum += __shfl_xor(s_sum, off);

    __shared__ float wpart[4];
    if (l == 0) wpart[w] = s_sum;
    __syncthreads();
    if (t == 0) {
        const float sim_v = (wpart[0] + wpart[1] + wpart[2] + wpart[3]) * (1.f / (32.f * 256.f));
        sim[(is_nn ? 0 : 4096) + i * 64 + j] = sim_v;
    }
}

// ---------------------------------------------------------------------------
// Fallback fp32 path (proven in round 1) if ws is too small for frag arrays.
// ---------------------------------------------------------------------------
__global__ __launch_bounds__(256) void sim_kernel_f32(
    const float* __restrict__ normal, const float* __restrict__ defect,
    float* __restrict__ sim)
{
    __shared__ float Bs[256 * 64];
    const int t = threadIdx.x;
    const int pair = blockIdx.x;
    const int i = pair >> 7;
    const int j2 = pair & 127;
    const bool is_nn = (j2 < 64);
    const int j = is_nn ? j2 : (j2 - 64);
    const float* bsrc = is_nn ? normal : defect;

    {
        const float4* bp = (const float4*)(bsrc + ((size_t)j * 256 + t) * 64);
        float4 bv[16];
        float ss = 0.f;
        #pragma unroll
        for (int k = 0; k < 16; ++k) {
            bv[k] = bp[k];
            ss += bv[k].x*bv[k].x + bv[k].y*bv[k].y + bv[k].z*bv[k].z + bv[k].w*bv[k].w;
        }
        const float inv = 1.f / (sqrtf(ss) + EPS);
        float4* bq = (float4*)&Bs[t * 64];
        #pragma unroll
        for (int k = 0; k < 16; ++k) {
            float4 v = bv[k];
            v.x *= inv; v.y *= inv; v.z *= inv; v.w *= inv;
            bq[k] = v;
        }
    }
    float a[64];
    {
        const float4* ap = (const float4*)(normal + ((size_t)i * 256 + t) * 64);
        float ss = 0.f;
        #pragma unroll
        for (int k = 0; k < 16; ++k) {
            float4 v = ap[k];
            a[4*k+0] = v.x; a[4*k+1] = v.y; a[4*k+2] = v.z; a[4*k+3] = v.w;
            ss += v.x*v.x + v.y*v.y + v.z*v.z + v.w*v.w;
        }
        const float inv = 1.f / (sqrtf(ss) + EPS);
        #pragma unroll
        for (int d = 0; d < 64; ++d) a[d] *= inv;
    }
    __syncthreads();
    float maxv = -1e30f;
    #pragma unroll 2
    for (int q = 0; q < 256; ++q) {
        const float4* bq = (const float4*)&Bs[q * 64];
        float acc0 = 0.f, acc1 = 0.f;
        #pragma unroll
        for (int k = 0; k < 8; ++k) {
            float4 b0 = bq[k];
            float4 b1 = bq[k + 8];
            acc0 += a[4*k+0]*b0.x + a[4*k+1]*b0.y + a[4*k+2]*b0.z + a[4*k+3]*b0.w;
            acc1 += a[4*(k+8)+0]*b1.x + a[4*(k+8)+1]*b1.y + a[4*(k+8)+2]*b1.z + a[4*(k+8)+3]*b1.w;
        }
        maxv = fmaxf(maxv, acc0 + acc1);
    }
    __syncthreads();
    float s = maxv;
    #pragma unroll
    for (int off = 32; off > 0; off >>= 1) s += __shfl_down(s, off);
    const int wid = t >> 6;
    if ((t & 63) == 0) Bs[wid] = s;
    __syncthreads();
    if (t == 0) {
        const float sim_v = (Bs[0] + Bs[1] + Bs[2] + Bs[3]) * (1.f / 256.f);
        sim[(is_nn ? 0 : 4096) + i * 64 + j] = sim_v;
    }
}

__global__ __launch_bounds__(256) void stats_kernel(const float* __restrict__ sim,
                                                    float* __restrict__ out)
{
    const int t = threadIdx.x;
    double snn = 0, qnn = 0, snd = 0, qnd = 0;
    for (int k = t; k < 4096; k += 256) {
        const int r = k >> 6, c = k & 63;
        const float vnn = sim[k];
        if (r != c) { snn += vnn; qnn += (double)vnn * vnn; }
        const float vnd = sim[4096 + k];
        snd += vnd; qnd += (double)vnd * vnd;
    }
    #pragma unroll
    for (int off = 32; off > 0; off >>= 1) {
        snn += __shfl_down(snn, off);
        qnn += __shfl_down(qnn, off);
        snd += __shfl_down(snd, off);
        qnd += __shfl_down(qnd, off);
    }
    __shared__ double red[4][4];
    const int wid = t >> 6;
    if ((t & 63) == 0) { red[0][wid] = snn; red[1][wid] = qnn; red[2][wid] = snd; red[3][wid] = qnd; }
    __syncthreads();
    if (t == 0) {
        const double SN = red[0][0] + red[0][1] + red[0][2] + red[0][3];
        const double QN = red[1][0] + red[1][1] + red[1][2] + red[1][3];
        const double SD = red[2][0] + red[2][1] + red[2][2] + red[2][3];
        const double QD = red[3][0] + red[3][1] + red[3][2] + red[3][3];
        const double cnt = 64.0 * 63.0;
        const double mu_nn = SN / cnt;
        double var_nn = (QN - cnt * mu_nn * mu_nn) / (cnt - 1.0);
        if (var_nn < 0) var_nn = 0;
        const double sig_nn = sqrt(var_nn);
        const double mu_nd = SD / 4096.0;
        double var_nd = (QD - 4096.0 * mu_nd * mu_nd) / 4095.0;
        if (var_nd < 0) var_nd = 0;
        const double sig_nd = sqrt(var_nd);
        const double sep = (mu_nn - mu_nd) / (sig_nn + sig_nd + 1e-8);
        out[0] = (float)(-sep);
    }
}

extern "C" void kernel_launch(void* const* d_in, const int* in_sizes, int n_in,
                              void* d_out, int out_size, void* d_ws, size_t ws_size,
                              hipStream_t stream) {
    const float* normal = (const float*)d_in[0];
    const float* defect = (const float*)d_in[1];
    float* out = (float*)d_out;

    const size_t FRAG = (size_t)64 * 8 * 4 * 64 * 8;          // shorts per array
    const size_t need = FRAG * 4 * sizeof(unsigned short) + 8192 * sizeof(float);

    if (ws_size >= need) {
        unsigned short* base = (unsigned short*)d_ws;
        unsigned short* fNh = base;
        unsigned short* fNl = base + FRAG;
        unsigned short* fDh = base + 2 * FRAG;
        unsigned short* fDl = base + 3 * FRAG;
        float* sim = (float*)(base + 4 * FRAG);

        prep_kernel<<<128, 256, 0, stream>>>(normal, defect, fNh, fNl, fDh, fDl);
        mfma_sim_kernel<<<8192, 256, 0, stream>>>(fNh, fNl, fDh, fDl, sim);
        stats_kernel<<<1, 256, 0, stream>>>(sim, out);
    } else {
        float* sim = (float*)d_ws;  // 32 KB
        sim_kernel_f32<<<8192, 256, 0, stream>>>(normal, defect, sim);
        stats_kernel<<<1, 256, 0, stream>>>(sim, out);
    }
}